// Round 2
// baseline (965.286 us; speedup 1.0000x reference)
//
#include <hip/hip_runtime.h>

// ---------------------------------------------------------------------------
// Spectral conv: out = irfft2( rfft2(x) * (w_real + i*w_imag) )
// B=16, C=64, H=256, W=256, WF=129.
//
// Pipeline (in-place in d_out, no workspace):
//   K1: per row-PAIR r2c FFT-256 (two real rows packed into one complex FFT,
//       untangled after), each row packed into 256 floats:
//       [X0.re, X128.re, X1.re, X1.im, ..., X127.re, X127.im]
//   K2: per packed column-pair: fwd complex FFT-256 over H, spectral multiply
//       (x 1/65536), inv complex FFT-256. Pair 0 packs the two REAL columns
//       (wf=0, wf=128); inverse side uses Hermitian-projected weights so the
//       stored pair-0 slots hold Re(z0), Re(z128) (c2r ignores those imags).
//   K3: per row-PAIR c2r (Hermitian rebuild of two rows into one complex ifft).
//
// FFT: Stockham radix-4, 4 stages, 64 lanes x 4 complex per wave, LDS
// ping-pong, i+(i>>4) pad swizzle. Twiddles precomputed per-lane in registers
// (inverse = conjugate). All intra-FFT syncs are wave-level (no s_barrier).
// ---------------------------------------------------------------------------

#define PHYS(i) ((i) + ((i) >> 4))   // 256 logical -> 272 physical float2

__device__ __forceinline__ float2 cmulf(float2 a, float2 b) {
    return make_float2(fmaf(a.x, b.x, -a.y * b.y), fmaf(a.x, b.y, a.y * b.x));
}

__device__ __forceinline__ void wave_sync() {
    // All LDS traffic here is wave-private; lockstep wave + drained lgkm
    // counter makes cross-lane LDS results visible without s_barrier.
    asm volatile("s_waitcnt lgkmcnt(0)" ::: "memory");
    __builtin_amdgcn_wave_barrier();
}

// Per-lane twiddles for stages Ns=4,16,64 (stage Ns=1 is twiddle-free),
// forward direction (dir=-1). Inverse uses the conjugate.
struct Tw {
    float2 a1, a2, a3;   // Ns=4
    float2 b1, b2, b3;   // Ns=16
    float2 c1, c2, c3;   // Ns=64
};

__device__ __forceinline__ void tw_one(int lane, int Ns, float2& w1, float2& w2, float2& w3) {
    int r = lane & (Ns - 1);
    float th = -6.283185307179586f * (float)r / (float)(4 * Ns);
    float s1, c1;
    __sincosf(th, &s1, &c1);
    w1 = make_float2(c1, s1);
    w2 = make_float2(c1 * c1 - s1 * s1, 2.0f * c1 * s1);
    w3 = make_float2(w2.x * c1 - w2.y * s1, w2.y * c1 + w2.x * s1);
}

__device__ __forceinline__ Tw make_tw(int lane) {
    Tw t;
    tw_one(lane, 4,  t.a1, t.a2, t.a3);
    tw_one(lane, 16, t.b1, t.b2, t.b3);
    tw_one(lane, 64, t.c1, t.c2, t.c3);
    return t;
}

// One Stockham radix-4 stage. DIR=-1 forward, +1 inverse (unnormalized).
// For DIR=+1 pass conjugated twiddles.
template<int NS, int DIR>
__device__ __forceinline__ void stage(const float2* s, float2* d, int j,
                                      float2 w1, float2 w2, float2 w3)
{
    float2 v0 = s[PHYS(j)];
    float2 v1 = s[PHYS(j + 64)];
    float2 v2 = s[PHYS(j + 128)];
    float2 v3 = s[PHYS(j + 192)];
    if (NS > 1) {
        v1 = cmulf(v1, w1);
        v2 = cmulf(v2, w2);
        v3 = cmulf(v3, w3);
    }
    float t0x = v0.x + v2.x, t0y = v0.y + v2.y;
    float t1x = v0.x - v2.x, t1y = v0.y - v2.y;
    float t2x = v1.x + v3.x, t2y = v1.y + v3.y;
    float t3x = v1.x - v3.x, t3y = v1.y - v3.y;
    // DIR*(i*t3)
    float ix = (DIR < 0) ? t3y : -t3y;
    float iy = (DIR < 0) ? -t3x : t3x;
    int r = j & (NS - 1);
    int base = ((j & ~(NS - 1)) << 2) | r;
    d[PHYS(base)]          = make_float2(t0x + t2x, t0y + t2y);
    d[PHYS(base + NS)]     = make_float2(t1x + ix, t1y + iy);
    d[PHYS(base + 2*NS)]   = make_float2(t0x - t2x, t0y - t2y);
    d[PHYS(base + 3*NS)]   = make_float2(t1x - ix, t1y - iy);
}

// 4-stage FFT-256 on a wave-private ping-pong pair (b0 holds input; result
// ends in b0 again since 4 stages = even number of swaps). FWD: pass fwd
// twiddles; INV: conjugates are formed here from the fwd set.
template<int DIR>
__device__ __forceinline__ void fft256(float2* b0, float2* b1, int lane, const Tw& t)
{
    const float sg = (DIR < 0) ? 1.0f : -1.0f;
    float2 a1 = make_float2(t.a1.x, sg * t.a1.y), a2 = make_float2(t.a2.x, sg * t.a2.y),
           a3 = make_float2(t.a3.x, sg * t.a3.y);
    float2 bb1 = make_float2(t.b1.x, sg * t.b1.y), bb2 = make_float2(t.b2.x, sg * t.b2.y),
           bb3 = make_float2(t.b3.x, sg * t.b3.y);
    float2 cc1 = make_float2(t.c1.x, sg * t.c1.y), cc2 = make_float2(t.c2.x, sg * t.c2.y),
           cc3 = make_float2(t.c3.x, sg * t.c3.y);
    wave_sync();
    stage<1,  DIR>(b0, b1, lane, a1, a1, a1);
    wave_sync();
    stage<4,  DIR>(b1, b0, lane, a1, a2, a3);
    wave_sync();
    stage<16, DIR>(b0, b1, lane, bb1, bb2, bb3);
    wave_sync();
    stage<64, DIR>(b1, b0, lane, cc1, cc2, cc3);
    wave_sync();
}

// ---------------- K1: row-pair r2c, packed output ----------------
__global__ __launch_bounds__(256) void k_rows_fwd(const float* __restrict__ x,
                                                  float* __restrict__ ws)
{
    __shared__ float2 buf[2][4][272];
    const int lane = threadIdx.x & 63;
    const int wv   = threadIdx.x >> 6;
    const int rp   = blockIdx.x * 4 + wv;            // row pair [0, B*C*H/2)
    const float* srcA = x + (size_t)rp * 512;        // row 2*rp
    const float* srcB = srcA + 256;                  // row 2*rp+1

    Tw tw = make_tw(lane);

    float4 av = *(const float4*)(srcA + lane * 4);
    float4 bv = *(const float4*)(srcB + lane * 4);
    float2* B0 = buf[0][wv];
    float2* B1 = buf[1][wv];
    B0[PHYS(4*lane + 0)] = make_float2(av.x, bv.x);
    B0[PHYS(4*lane + 1)] = make_float2(av.y, bv.y);
    B0[PHYS(4*lane + 2)] = make_float2(av.z, bv.z);
    B0[PHYS(4*lane + 3)] = make_float2(av.w, bv.w);

    fft256<-1>(B0, B1, lane, tw);

    // Untangle Z = A + i*B into packed half-spectra of rows a and b.
    const float2* F = B0;
    float4 oa, ob;
    if (lane == 0) {
        float2 Z0 = F[PHYS(0)], Z128 = F[PHYS(128)];
        float2 Z1 = F[PHYS(1)], Zm = F[PHYS(255)];
        // A[1] = (Z1 + conj(Zm))/2 ; B[1] = -i*(Z1 - conj(Zm))/2
        float2 A1 = make_float2(0.5f * (Z1.x + Zm.x), 0.5f * (Z1.y - Zm.y));
        float2 Bd = make_float2(0.5f * (Z1.x - Zm.x), 0.5f * (Z1.y + Zm.y));
        float2 B1f = make_float2(Bd.y, -Bd.x);
        oa = make_float4(Z0.x, Z128.x, A1.x, A1.y);
        ob = make_float4(Z0.y, Z128.y, B1f.x, B1f.y);
    } else {
        int k0 = 2 * lane;
        float2 Zk0 = F[PHYS(k0)],     Zm0 = F[PHYS(256 - k0)];
        float2 Zk1 = F[PHYS(k0 + 1)], Zm1 = F[PHYS(255 - k0)];
        float2 A0 = make_float2(0.5f * (Zk0.x + Zm0.x), 0.5f * (Zk0.y - Zm0.y));
        float2 D0 = make_float2(0.5f * (Zk0.x - Zm0.x), 0.5f * (Zk0.y + Zm0.y));
        float2 Bf0 = make_float2(D0.y, -D0.x);
        float2 A1 = make_float2(0.5f * (Zk1.x + Zm1.x), 0.5f * (Zk1.y - Zm1.y));
        float2 D1 = make_float2(0.5f * (Zk1.x - Zm1.x), 0.5f * (Zk1.y + Zm1.y));
        float2 Bf1 = make_float2(D1.y, -D1.x);
        oa = make_float4(A0.x, A0.y, A1.x, A1.y);
        ob = make_float4(Bf0.x, Bf0.y, Bf1.x, Bf1.y);
    }
    float* dstA = ws + (size_t)rp * 512;
    *(float4*)(dstA + lane * 4)       = oa;
    *(float4*)(dstA + 256 + lane * 4) = ob;
}

// ---------------- K2: column FFT + spectral multiply + inverse ----------------
__global__ __launch_bounds__(512) void k_cols(float* __restrict__ ws,
                                              const float* __restrict__ wre,
                                              const float* __restrict__ wim)
{
    __shared__ float2 buf[2][8][272];                // 34.8 KiB
    const int tid  = threadIdx.x;
    const int lane = tid & 63;
    const int wv   = tid >> 6;                       // local pair 0..7
    const int grp  = blockIdx.x & 15;                // pair-group
    const int img  = blockIdx.x >> 4;                // b*C + c
    const int c    = img & 63;
    const int p0   = grp * 8;
    const int pair = p0 + wv;
    float* base = ws + (size_t)img * 65536;

    Tw tw = make_tw(lane);

    // Prefetch this wave's spectral weights (consumed after the fwd FFT;
    // scattered 516B-stride reads, latency hidden under the FFT).
    const int cbase = c * 256;
    float pwr[4], pwi[4];
#pragma unroll
    for (int t = 0; t < 4; ++t) {
        int ik = (cbase + lane + 64 * t) * 129 + pair;
        pwr[t] = wre[ik];
        pwi[t] = wim[ik];
    }

    // Load 256 rows x 16 floats (8 complex pairs), coalesced float4 (cross-wave).
    for (int q = tid; q < 1024; q += 512) {
        int h = q >> 2, j4 = q & 3;
        float4 v = *(const float4*)(base + h * 256 + p0 * 2 + j4 * 4);
        buf[0][2*j4    ][PHYS(h)] = make_float2(v.x, v.y);
        buf[0][2*j4 + 1][PHYS(h)] = make_float2(v.z, v.w);
    }
    __syncthreads();

    float2* B0 = buf[0][wv];
    float2* B1 = buf[1][wv];
    fft256<-1>(B0, B1, lane, tw);

    const float g = 1.0f / 65536.0f;                 // ifft2 normalization
    {
        const float2* S = B0;
        float2* D = B1;
        if (pair == 0) {
            // T = R0 + i*R128 (two real columns). Untangle, multiply by
            // Hermitian-projected weights, repack -> ifft gives
            // Re(z0) + i*Re(z128) directly.
#pragma unroll
            for (int t = 0; t < 4; ++t) {
                int k = lane + 64 * t;
                int m = (256 - k) & 255;
                float2 Sk = S[PHYS(k)], Sm = S[PHYS(m)];
                float2 S0   = make_float2(0.5f * (Sk.x + Sm.x), 0.5f * (Sk.y - Sm.y));
                float2 Dk   = make_float2(0.5f * (Sk.x - Sm.x), 0.5f * (Sk.y + Sm.y));
                float2 S128 = make_float2(Dk.y, -Dk.x);          // -i * Dk
                int ik = (cbase + k) * 129, im = (cbase + m) * 129;
                float2 A0   = make_float2(0.5f * g * (wre[ik] + wre[im]),
                                          0.5f * g * (wim[ik] - wim[im]));
                float2 A128 = make_float2(0.5f * g * (wre[ik + 128] + wre[im + 128]),
                                          0.5f * g * (wim[ik + 128] - wim[im + 128]));
                float2 y0 = cmulf(S0, A0);
                float2 y1 = cmulf(S128, A128);
                D[PHYS(k)] = make_float2(y0.x - y1.y, y0.y + y1.x); // y0 + i*y1
            }
        } else {
#pragma unroll
            for (int t = 0; t < 4; ++t) {
                int k = lane + 64 * t;
                float2 Sk = S[PHYS(k)];
                float2 W = make_float2(g * pwr[t], g * pwi[t]);
                D[PHYS(k)] = cmulf(Sk, W);
            }
        }
    }
    // Result of multiply sits in B1; inverse FFT wants input in its b0 slot.
    fft256<+1>(B1, B0, lane, tw);

    __syncthreads();
    for (int q = tid; q < 1024; q += 512) {
        int h = q >> 2, j4 = q & 3;
        float2 a = buf[1][2*j4    ][PHYS(h)];
        float2 b = buf[1][2*j4 + 1][PHYS(h)];
        *(float4*)(base + h * 256 + p0 * 2 + j4 * 4) = make_float4(a.x, a.y, b.x, b.y);
    }
}

// ---------------- K3: row-pair c2r, in place ----------------
__global__ __launch_bounds__(256) void k_rows_inv(float* __restrict__ ws)
{
    __shared__ float2 buf[2][4][272];
    const int lane = threadIdx.x & 63;
    const int wv   = threadIdx.x >> 6;
    const int rp   = blockIdx.x * 4 + wv;
    float* rowA = ws + (size_t)rp * 512;
    float* rowB = rowA + 256;

    Tw tw = make_tw(lane);

    float4 va = *(const float4*)(rowA + lane * 4);
    float4 vb = *(const float4*)(rowB + lane * 4);
    float2* B0 = buf[0][wv];
    float2* B1 = buf[1][wv];
    // Build V[k] = Ya[k] + i*Yb[k] (Hermitian extensions of both packed rows);
    // ifft(V) = ya[n] + i*yb[n], both real.
    if (lane == 0) {
        // packed: [z0.re, z128.re, z1.re, z1.im]
        B0[PHYS(0)]   = make_float2(va.x, vb.x);
        B0[PHYS(128)] = make_float2(va.y, vb.y);
        B0[PHYS(1)]   = make_float2(va.z - vb.w, va.w + vb.z);
        B0[PHYS(255)] = make_float2(va.z + vb.w, -va.w + vb.z);
    } else {
        int k0 = 2 * lane;
        B0[PHYS(k0)]        = make_float2(va.x - vb.y, va.y + vb.x);
        B0[PHYS(256 - k0)]  = make_float2(va.x + vb.y, -va.y + vb.x);
        B0[PHYS(k0 + 1)]    = make_float2(va.z - vb.w, va.w + vb.z);
        B0[PHYS(255 - k0)]  = make_float2(va.z + vb.w, -va.w + vb.z);
    }

    fft256<+1>(B0, B1, lane, tw);

    const float2* F = B0;
    float2 f0 = F[PHYS(4*lane)], f1 = F[PHYS(4*lane + 1)];
    float2 f2 = F[PHYS(4*lane + 2)], f3 = F[PHYS(4*lane + 3)];
    *(float4*)(rowA + lane * 4) = make_float4(f0.x, f1.x, f2.x, f3.x);
    *(float4*)(rowB + lane * 4) = make_float4(f0.y, f1.y, f2.y, f3.y);
}

extern "C" void kernel_launch(void* const* d_in, const int* in_sizes, int n_in,
                              void* d_out, int out_size, void* d_ws, size_t ws_size,
                              hipStream_t stream)
{
    (void)in_sizes; (void)n_in; (void)d_ws; (void)ws_size; (void)out_size;
    const float* x   = (const float*)d_in[0];
    const float* wre = (const float*)d_in[1];
    const float* wim = (const float*)d_in[2];
    float* out = (float*)d_out;

    // B*C*H/2 = 131072 row pairs, 4 per block
    k_rows_fwd<<<dim3(32768), dim3(256), 0, stream>>>(x, out);
    // 1024 images x 16 pair-groups
    k_cols<<<dim3(16384), dim3(512), 0, stream>>>(out, wre, wim);
    k_rows_inv<<<dim3(32768), dim3(256), 0, stream>>>(out);
}

// Round 5
// 692.044 us; speedup vs baseline: 1.3948x; 1.3948x over previous
//
#include <hip/hip_runtime.h>

// ---------------------------------------------------------------------------
// Spectral conv: out = irfft2( rfft2(x) * (w_real + i*w_imag) )
// B=16, C=64, H=256, W=256, WF=129.
//
// Pipeline (spectrum in-place in d_out; d_ws holds transposed weights):
//   K0: weight transpose -> wt[c][wf][h] float2, coalesced for K2.
//   K1: per row-PAIR r2c FFT-256 (two real rows in one complex FFT), packed
//       per row: [X0.re, X128.re, X1.re, X1.im, ..., X127.re, X127.im]
//   K2: per packed column-pair: fwd complex FFT-256 over H, spectral multiply
//       (x 1/65536), inv complex FFT-256. Pair 0 packs the two REAL columns
//       (wf=0, wf=128); Hermitian-projected weights keep pair-0 slots real.
//   K3: per row-PAIR c2r (Hermitian rebuild of two rows into one complex ifft).
//
// FFT: Stockham radix-4, 4 stages, 64 lanes x 4 complex per wave, LDS
// ping-pong, i+(i>>4) pad swizzle, register twiddles, wave-level syncs only.
// ---------------------------------------------------------------------------

#define PHYS(i) ((i) + ((i) >> 4))   // 256 logical -> 272 physical float2

// clang ext-vector alias: __builtin_nontemporal_* requires a true vector type
// (HIP's float4 is a class and is rejected).
typedef float fvec4 __attribute__((ext_vector_type(4)));

__device__ __forceinline__ float4 nt_load4(const float* p) {
    fvec4 v = __builtin_nontemporal_load((const fvec4*)p);
    return make_float4(v.x, v.y, v.z, v.w);
}
__device__ __forceinline__ void nt_store4(float* p, float4 v) {
    fvec4 t;
    t.x = v.x; t.y = v.y; t.z = v.z; t.w = v.w;
    __builtin_nontemporal_store(t, (fvec4*)p);
}

__device__ __forceinline__ float2 cmulf(float2 a, float2 b) {
    return make_float2(fmaf(a.x, b.x, -a.y * b.y), fmaf(a.x, b.y, a.y * b.x));
}

__device__ __forceinline__ void wave_sync() {
    asm volatile("s_waitcnt lgkmcnt(0)" ::: "memory");
    __builtin_amdgcn_wave_barrier();
}

struct Tw {
    float2 a1, a2, a3;   // Ns=4
    float2 b1, b2, b3;   // Ns=16
    float2 c1, c2, c3;   // Ns=64
};

__device__ __forceinline__ void tw_one(int lane, int Ns, float2& w1, float2& w2, float2& w3) {
    int r = lane & (Ns - 1);
    float th = -6.283185307179586f * (float)r / (float)(4 * Ns);
    float s1, c1;
    __sincosf(th, &s1, &c1);
    w1 = make_float2(c1, s1);
    w2 = make_float2(c1 * c1 - s1 * s1, 2.0f * c1 * s1);
    w3 = make_float2(w2.x * c1 - w2.y * s1, w2.y * c1 + w2.x * s1);
}

__device__ __forceinline__ Tw make_tw(int lane) {
    Tw t;
    tw_one(lane, 4,  t.a1, t.a2, t.a3);
    tw_one(lane, 16, t.b1, t.b2, t.b3);
    tw_one(lane, 64, t.c1, t.c2, t.c3);
    return t;
}

template<int NS, int DIR>
__device__ __forceinline__ void stage(const float2* s, float2* d, int j,
                                      float2 w1, float2 w2, float2 w3)
{
    float2 v0 = s[PHYS(j)];
    float2 v1 = s[PHYS(j + 64)];
    float2 v2 = s[PHYS(j + 128)];
    float2 v3 = s[PHYS(j + 192)];
    if (NS > 1) {
        v1 = cmulf(v1, w1);
        v2 = cmulf(v2, w2);
        v3 = cmulf(v3, w3);
    }
    float t0x = v0.x + v2.x, t0y = v0.y + v2.y;
    float t1x = v0.x - v2.x, t1y = v0.y - v2.y;
    float t2x = v1.x + v3.x, t2y = v1.y + v3.y;
    float t3x = v1.x - v3.x, t3y = v1.y - v3.y;
    float ix = (DIR < 0) ? t3y : -t3y;
    float iy = (DIR < 0) ? -t3x : t3x;
    int r = j & (NS - 1);
    int base = ((j & ~(NS - 1)) << 2) | r;
    d[PHYS(base)]          = make_float2(t0x + t2x, t0y + t2y);
    d[PHYS(base + NS)]     = make_float2(t1x + ix, t1y + iy);
    d[PHYS(base + 2*NS)]   = make_float2(t0x - t2x, t0y - t2y);
    d[PHYS(base + 3*NS)]   = make_float2(t1x - ix, t1y - iy);
}

template<int DIR>
__device__ __forceinline__ void fft256(float2* b0, float2* b1, int lane, const Tw& t)
{
    const float sg = (DIR < 0) ? 1.0f : -1.0f;
    float2 a1 = make_float2(t.a1.x, sg * t.a1.y), a2 = make_float2(t.a2.x, sg * t.a2.y),
           a3 = make_float2(t.a3.x, sg * t.a3.y);
    float2 bb1 = make_float2(t.b1.x, sg * t.b1.y), bb2 = make_float2(t.b2.x, sg * t.b2.y),
           bb3 = make_float2(t.b3.x, sg * t.b3.y);
    float2 cc1 = make_float2(t.c1.x, sg * t.c1.y), cc2 = make_float2(t.c2.x, sg * t.c2.y),
           cc3 = make_float2(t.c3.x, sg * t.c3.y);
    wave_sync();
    stage<1,  DIR>(b0, b1, lane, a1, a1, a1);
    wave_sync();
    stage<4,  DIR>(b1, b0, lane, a1, a2, a3);
    wave_sync();
    stage<16, DIR>(b0, b1, lane, bb1, bb2, bb3);
    wave_sync();
    stage<64, DIR>(b1, b0, lane, cc1, cc2, cc3);
    wave_sync();
}

// ---------------- K0: weight transpose -> wt[c][wf][h] float2 ----------------
__global__ __launch_bounds__(256) void k_wt(const float* __restrict__ wre,
                                            const float* __restrict__ wim,
                                            float2* __restrict__ wt)
{
    __shared__ float tr[32 * 129];
    __shared__ float ti[32 * 129];
    const int c  = blockIdx.x >> 3;
    const int h0 = (blockIdx.x & 7) * 32;
    const float* pr = wre + ((size_t)c * 256 + h0) * 129;
    const float* pi = wim + ((size_t)c * 256 + h0) * 129;
    for (int idx = threadIdx.x; idx < 32 * 129; idx += 256) {
        tr[idx] = pr[idx];
        ti[idx] = pi[idx];
    }
    __syncthreads();
    for (int idx = threadIdx.x; idx < 129 * 32; idx += 256) {
        int wf = idx >> 5, hl = idx & 31;
        wt[((size_t)c * 129 + wf) * 256 + h0 + hl] =
            make_float2(tr[hl * 129 + wf], ti[hl * 129 + wf]);
    }
}

// ---------------- K1: row-pair r2c, packed output ----------------
__global__ __launch_bounds__(256) void k_rows_fwd(const float* __restrict__ x,
                                                  float* __restrict__ ws)
{
    __shared__ float2 buf[2][4][272];
    const int lane = threadIdx.x & 63;
    const int wv   = threadIdx.x >> 6;
    const int rp   = blockIdx.x * 4 + wv;            // row pair [0, B*C*H/2)
    const float* srcA = x + (size_t)rp * 512;
    const float* srcB = srcA + 256;

    Tw tw = make_tw(lane);

    // x is read exactly once -> nontemporal (don't evict spectrum from L2/L3)
    float4 av = nt_load4(srcA + lane * 4);
    float4 bv = nt_load4(srcB + lane * 4);
    float2* B0 = buf[0][wv];
    float2* B1 = buf[1][wv];
    B0[PHYS(4*lane + 0)] = make_float2(av.x, bv.x);
    B0[PHYS(4*lane + 1)] = make_float2(av.y, bv.y);
    B0[PHYS(4*lane + 2)] = make_float2(av.z, bv.z);
    B0[PHYS(4*lane + 3)] = make_float2(av.w, bv.w);

    fft256<-1>(B0, B1, lane, tw);

    const float2* F = B0;
    float4 oa, ob;
    if (lane == 0) {
        float2 Z0 = F[PHYS(0)], Z128 = F[PHYS(128)];
        float2 Z1 = F[PHYS(1)], Zm = F[PHYS(255)];
        float2 A1 = make_float2(0.5f * (Z1.x + Zm.x), 0.5f * (Z1.y - Zm.y));
        float2 Bd = make_float2(0.5f * (Z1.x - Zm.x), 0.5f * (Z1.y + Zm.y));
        float2 B1f = make_float2(Bd.y, -Bd.x);
        oa = make_float4(Z0.x, Z128.x, A1.x, A1.y);
        ob = make_float4(Z0.y, Z128.y, B1f.x, B1f.y);
    } else {
        int k0 = 2 * lane;
        float2 Zk0 = F[PHYS(k0)],     Zm0 = F[PHYS(256 - k0)];
        float2 Zk1 = F[PHYS(k0 + 1)], Zm1 = F[PHYS(255 - k0)];
        float2 A0 = make_float2(0.5f * (Zk0.x + Zm0.x), 0.5f * (Zk0.y - Zm0.y));
        float2 D0 = make_float2(0.5f * (Zk0.x - Zm0.x), 0.5f * (Zk0.y + Zm0.y));
        float2 Bf0 = make_float2(D0.y, -D0.x);
        float2 A1 = make_float2(0.5f * (Zk1.x + Zm1.x), 0.5f * (Zk1.y - Zm1.y));
        float2 D1 = make_float2(0.5f * (Zk1.x - Zm1.x), 0.5f * (Zk1.y + Zm1.y));
        float2 Bf1 = make_float2(D1.y, -D1.x);
        oa = make_float4(A0.x, A0.y, A1.x, A1.y);
        ob = make_float4(Bf0.x, Bf0.y, Bf1.x, Bf1.y);
    }
    float* dstA = ws + (size_t)rp * 512;
    *(float4*)(dstA + lane * 4)       = oa;
    *(float4*)(dstA + 256 + lane * 4) = ob;
}

// ---------------- K2: column FFT + spectral multiply + inverse ----------------
template<bool USEWT>
__global__ __launch_bounds__(512) void k_cols(float* __restrict__ ws,
                                              const float* __restrict__ wre,
                                              const float* __restrict__ wim,
                                              const float2* __restrict__ wt)
{
    __shared__ float2 buf[2][8][272];                // 34.8 KiB
    const int tid  = threadIdx.x;
    const int lane = tid & 63;
    const int wv   = tid >> 6;                       // local pair 0..7
    // XCD-aware swizzle (16384 % 8 == 0): each XCD gets a contiguous chunk,
    // so adjacent-grp blocks (sharing 128B spectrum lines) share an L2.
    const int nwg  = gridDim.x;
    const int L    = (blockIdx.x & 7) * (nwg >> 3) + (blockIdx.x >> 3);
    const int grp  = L & 15;                         // pair-group
    const int img  = L >> 4;                         // b*C + c
    const int c    = img & 63;
    const int p0   = grp * 8;
    const int pair = p0 + wv;
    float* base = ws + (size_t)img * 65536;

    Tw tw = make_tw(lane);

    // Prefetch this wave's spectral weights (consumed after the fwd FFT).
    const int cbase = c * 256;
    float2 pw[4];
    if (USEWT) {
        const float2* wp = wt + ((size_t)c * 129 + pair) * 256;
#pragma unroll
        for (int t = 0; t < 4; ++t) pw[t] = wp[lane + 64 * t];   // coalesced
    } else {
#pragma unroll
        for (int t = 0; t < 4; ++t) {
            int ik = (cbase + lane + 64 * t) * 129 + pair;
            pw[t] = make_float2(wre[ik], wim[ik]);               // scattered
        }
    }

    // Load 256 rows x 16 floats (8 complex pairs), coalesced float4.
    for (int q = tid; q < 1024; q += 512) {
        int h = q >> 2, j4 = q & 3;
        float4 v = *(const float4*)(base + h * 256 + p0 * 2 + j4 * 4);
        buf[0][2*j4    ][PHYS(h)] = make_float2(v.x, v.y);
        buf[0][2*j4 + 1][PHYS(h)] = make_float2(v.z, v.w);
    }
    __syncthreads();

    float2* B0 = buf[0][wv];
    float2* B1 = buf[1][wv];
    fft256<-1>(B0, B1, lane, tw);

    const float g = 1.0f / 65536.0f;                 // ifft2 normalization
    {
        const float2* S = B0;
        float2* D = B1;
        if (pair == 0) {
            // T = R0 + i*R128 (two real columns). Untangle, multiply by
            // Hermitian-projected weights, repack.
#pragma unroll
            for (int t = 0; t < 4; ++t) {
                int k = lane + 64 * t;
                int m = (256 - k) & 255;
                float2 Sk = S[PHYS(k)], Sm = S[PHYS(m)];
                float2 S0   = make_float2(0.5f * (Sk.x + Sm.x), 0.5f * (Sk.y - Sm.y));
                float2 Dk   = make_float2(0.5f * (Sk.x - Sm.x), 0.5f * (Sk.y + Sm.y));
                float2 S128 = make_float2(Dk.y, -Dk.x);          // -i * Dk
                float2 wk0, wm0, wk128, wm128;
                if (USEWT) {
                    const float2* w0row   = wt + ((size_t)c * 129 +   0) * 256;
                    const float2* w128row = wt + ((size_t)c * 129 + 128) * 256;
                    wk0 = w0row[k];  wm0 = w0row[m];
                    wk128 = w128row[k];  wm128 = w128row[m];
                } else {
                    int ik = (cbase + k) * 129, im = (cbase + m) * 129;
                    wk0   = make_float2(wre[ik], wim[ik]);
                    wm0   = make_float2(wre[im], wim[im]);
                    wk128 = make_float2(wre[ik + 128], wim[ik + 128]);
                    wm128 = make_float2(wre[im + 128], wim[im + 128]);
                }
                float2 A0   = make_float2(0.5f * g * (wk0.x + wm0.x),
                                          0.5f * g * (wk0.y - wm0.y));
                float2 A128 = make_float2(0.5f * g * (wk128.x + wm128.x),
                                          0.5f * g * (wk128.y - wm128.y));
                float2 y0 = cmulf(S0, A0);
                float2 y1 = cmulf(S128, A128);
                D[PHYS(k)] = make_float2(y0.x - y1.y, y0.y + y1.x); // y0 + i*y1
            }
        } else {
#pragma unroll
            for (int t = 0; t < 4; ++t) {
                int k = lane + 64 * t;
                float2 Sk = S[PHYS(k)];
                float2 W = make_float2(g * pw[t].x, g * pw[t].y);
                D[PHYS(k)] = cmulf(Sk, W);
            }
        }
    }
    fft256<+1>(B1, B0, lane, tw);

    __syncthreads();
    for (int q = tid; q < 1024; q += 512) {
        int h = q >> 2, j4 = q & 3;
        float2 a = buf[1][2*j4    ][PHYS(h)];
        float2 b = buf[1][2*j4 + 1][PHYS(h)];
        *(float4*)(base + h * 256 + p0 * 2 + j4 * 4) = make_float4(a.x, a.y, b.x, b.y);
    }
}

// ---------------- K3: row-pair c2r, in place ----------------
__global__ __launch_bounds__(256) void k_rows_inv(float* __restrict__ ws)
{
    __shared__ float2 buf[2][4][272];
    const int lane = threadIdx.x & 63;
    const int wv   = threadIdx.x >> 6;
    const int rp   = blockIdx.x * 4 + wv;
    float* rowA = ws + (size_t)rp * 512;
    float* rowB = rowA + 256;

    Tw tw = make_tw(lane);

    float4 va = *(const float4*)(rowA + lane * 4);
    float4 vb = *(const float4*)(rowB + lane * 4);
    float2* B0 = buf[0][wv];
    float2* B1 = buf[1][wv];
    if (lane == 0) {
        B0[PHYS(0)]   = make_float2(va.x, vb.x);
        B0[PHYS(128)] = make_float2(va.y, vb.y);
        B0[PHYS(1)]   = make_float2(va.z - vb.w, va.w + vb.z);
        B0[PHYS(255)] = make_float2(va.z + vb.w, -va.w + vb.z);
    } else {
        int k0 = 2 * lane;
        B0[PHYS(k0)]        = make_float2(va.x - vb.y, va.y + vb.x);
        B0[PHYS(256 - k0)]  = make_float2(va.x + vb.y, -va.y + vb.x);
        B0[PHYS(k0 + 1)]    = make_float2(va.z - vb.w, va.w + vb.z);
        B0[PHYS(255 - k0)]  = make_float2(va.z + vb.w, -va.w + vb.z);
    }

    fft256<+1>(B0, B1, lane, tw);

    const float2* F = B0;
    float2 f0 = F[PHYS(4*lane)], f1 = F[PHYS(4*lane + 1)];
    float2 f2 = F[PHYS(4*lane + 2)], f3 = F[PHYS(4*lane + 3)];
    // Final output is never re-read on-device -> nontemporal stores.
    nt_store4(rowA + lane * 4, make_float4(f0.x, f1.x, f2.x, f3.x));
    nt_store4(rowB + lane * 4, make_float4(f0.y, f1.y, f2.y, f3.y));
}

extern "C" void kernel_launch(void* const* d_in, const int* in_sizes, int n_in,
                              void* d_out, int out_size, void* d_ws, size_t ws_size,
                              hipStream_t stream)
{
    (void)in_sizes; (void)n_in; (void)out_size;
    const float* x   = (const float*)d_in[0];
    const float* wre = (const float*)d_in[1];
    const float* wim = (const float*)d_in[2];
    float* out = (float*)d_out;
    float2* wt = (float2*)d_ws;

    const size_t wt_bytes = (size_t)64 * 129 * 256 * sizeof(float2);  // 16.9 MB
    const bool use_wt = (ws_size >= wt_bytes);

    if (use_wt) {
        // 64 c x 8 h-tiles
        k_wt<<<dim3(512), dim3(256), 0, stream>>>(wre, wim, wt);
    }
    // B*C*H/2 = 131072 row pairs, 4 per block
    k_rows_fwd<<<dim3(32768), dim3(256), 0, stream>>>(x, out);
    // 1024 images x 16 pair-groups
    if (use_wt)
        k_cols<true ><<<dim3(16384), dim3(512), 0, stream>>>(out, wre, wim, wt);
    else
        k_cols<false><<<dim3(16384), dim3(512), 0, stream>>>(out, wre, wim, wt);
    k_rows_inv<<<dim3(32768), dim3(256), 0, stream>>>(out);
}

// Round 7
// 632.125 us; speedup vs baseline: 1.5270x; 1.0948x over previous
//
#include <hip/hip_runtime.h>

// ---------------------------------------------------------------------------
// Spectral conv: out = irfft2( rfft2(x) * (w_real + i*w_imag) )
// B=16, C=64, H=256, W=256, WF=129.
//
// Pipeline (spectrum in-place in d_out; d_ws holds transposed weights):
//   K0: weight transpose -> wt[c][wf][h] float2.
//   K1: per row-PAIR r2c FFT-256 (Stockham/LDS, XOR-swizzled), packed rows.
//   K2: REGISTER-COLUMN FFT: 256=16x16 four-step. 16-lane group per packed
//       column-pair; 16 complex per lane in VGPRs; 16-pt DFTs in registers;
//       one conflict-free LDS 16x16 transpose per FFT. Spectral multiply in
//       registers (weights prefetched). Pair 0 = two packed real columns,
//       Hermitian-projected weights (one extra LDS exchange, rare).
//   K3: per row-PAIR c2r (Stockham/LDS, XOR-swizzled).
// ---------------------------------------------------------------------------

// XOR bank swizzle for the Stockham kernels: bijective on [0,256), makes all
// stage read/write patterns (Ns=1,4,16,64) conflict-free per 16-lane quarter.
#define PHX(i) ((i) ^ ((i) >> 2))

typedef float fvec4 __attribute__((ext_vector_type(4)));

__device__ __forceinline__ float4 nt_load4(const float* p) {
    fvec4 v = __builtin_nontemporal_load((const fvec4*)p);
    return make_float4(v.x, v.y, v.z, v.w);
}
__device__ __forceinline__ void nt_store4(float* p, float4 v) {
    fvec4 t;
    t.x = v.x; t.y = v.y; t.z = v.z; t.w = v.w;
    __builtin_nontemporal_store(t, (fvec4*)p);
}

__device__ __forceinline__ float2 cmulf(float2 a, float2 b) {
    return make_float2(fmaf(a.x, b.x, -a.y * b.y), fmaf(a.x, b.y, a.y * b.x));
}
__device__ __forceinline__ float2 cadd(float2 a, float2 b){ return make_float2(a.x+b.x, a.y+b.y); }
__device__ __forceinline__ float2 csub(float2 a, float2 b){ return make_float2(a.x-b.x, a.y-b.y); }
__device__ __forceinline__ float2 mulmi(float2 a){ return make_float2(a.y, -a.x); }   // *(-i)
__device__ __forceinline__ float2 mulpi(float2 a){ return make_float2(-a.y, a.x); }   // *(+i)

__device__ __forceinline__ void wave_sync() {
    asm volatile("s_waitcnt lgkmcnt(0)" ::: "memory");
    __builtin_amdgcn_wave_barrier();
}

// ======================= register FFT pieces (K2) ==========================

template<int DIR>
__device__ __forceinline__ void dft4(float2 x0, float2 x1, float2 x2, float2 x3,
                                     float2& y0, float2& y1, float2& y2, float2& y3)
{
    float2 s0 = cadd(x0, x2), d0 = csub(x0, x2);
    float2 s1 = cadd(x1, x3), d1 = csub(x1, x3);
    y0 = cadd(s0, s1);
    y2 = csub(s0, s1);
    float2 jd1 = (DIR < 0) ? mulmi(d1) : mulpi(d1);
    y1 = cadd(d0, jd1);
    y3 = csub(d0, jd1);
}

// twiddle multiply; (wr,wi) is the FORWARD (e^{-i*}) value; inverse conjugates
template<int DIR>
__device__ __forceinline__ float2 twd(float2 a, float wr, float wi) {
    return cmulf(a, make_float2(wr, (DIR < 0) ? wi : -wi));
}

// in-register 16-point DFT (DIT 4x4), v[n] -> V[k]
template<int DIR>
__device__ __forceinline__ void dft16(float2 v[16])
{
    const float C1 = 0.92387953251128674f;   // cos(pi/8)
    const float S1 = 0.38268343236508978f;   // sin(pi/8)
    const float R  = 0.70710678118654752f;   // cos(pi/4)
    float2 a0, a1, a2, a3;
    // stage 1: DFT4 over a for each b; twiddle w16^{b*c}
    dft4<DIR>(v[0], v[4], v[8],  v[12], a0, a1, a2, a3);
    float2 u00 = a0, u01 = a1, u02 = a2, u03 = a3;
    dft4<DIR>(v[1], v[5], v[9],  v[13], a0, a1, a2, a3);
    float2 u10 = a0;
    float2 u11 = twd<DIR>(a1,  C1, -S1);   // j=1
    float2 u12 = twd<DIR>(a2,   R,  -R);   // j=2
    float2 u13 = twd<DIR>(a3,  S1, -C1);   // j=3
    dft4<DIR>(v[2], v[6], v[10], v[14], a0, a1, a2, a3);
    float2 u20 = a0;
    float2 u21 = twd<DIR>(a1,   R,  -R);   // j=2
    float2 u22 = (DIR < 0) ? mulmi(a2) : mulpi(a2);  // j=4
    float2 u23 = twd<DIR>(a3,  -R,  -R);   // j=6
    dft4<DIR>(v[3], v[7], v[11], v[15], a0, a1, a2, a3);
    float2 u30 = a0;
    float2 u31 = twd<DIR>(a1,  S1, -C1);   // j=3
    float2 u32 = twd<DIR>(a2,  -R,  -R);   // j=6
    float2 u33 = twd<DIR>(a3, -C1,  S1);   // j=9
    // stage 2: DFT4 over b for each c; outputs V[c+4d]
    dft4<DIR>(u00, u10, u20, u30, v[0], v[4], v[8],  v[12]);
    dft4<DIR>(u01, u11, u21, u31, v[1], v[5], v[9],  v[13]);
    dft4<DIR>(u02, u12, u22, u32, v[2], v[6], v[10], v[14]);
    dft4<DIR>(u03, u13, u23, u33, v[3], v[7], v[11], v[15]);
}

// mid twiddle: v[k1] *= w256^{DIR * n2 * k1} via recurrence (1 sincos)
template<int DIR>
__device__ __forceinline__ void midtw(float2 v[16], int n2)
{
    float th = ((DIR < 0) ? -6.283185307179586f : 6.283185307179586f)
               * (float)n2 * (1.0f / 256.0f);
    float s, c;
    __sincosf(th, &s, &c);
    float2 base = make_float2(c, s);
    float2 w = base;
    v[1] = cmulf(v[1], w);
#pragma unroll
    for (int k = 2; k < 16; ++k) { w = cmulf(w, base); v[k] = cmulf(v[k], w); }
}

// group FFT-256: input lane l holds x[16*n1+l] in v[n1]; output v[k2]=X[l+16*k2].
// Ag = group's LDS area (>=271 float2, row stride 17 for the transpose).
template<int DIR>
__device__ __forceinline__ void gfft(float2 v[16], float2* Ag, int l)
{
    dft16<DIR>(v);
    midtw<DIR>(v, l);
    wave_sync();                       // prior reads of Ag done before clobber
#pragma unroll
    for (int k = 0; k < 16; ++k) Ag[l * 17 + k] = v[k];
    wave_sync();
#pragma unroll
    for (int n = 0; n < 16; ++n) v[n] = Ag[n * 17 + l];
    dft16<DIR>(v);
}

// ===================== Stockham pieces (K1/K3) =============================

struct Tw {
    float2 a1, a2, a3;   // Ns=4
    float2 b1, b2, b3;   // Ns=16
    float2 c1, c2, c3;   // Ns=64
};

__device__ __forceinline__ void tw_one(int lane, int Ns, float2& w1, float2& w2, float2& w3) {
    int r = lane & (Ns - 1);
    float th = -6.283185307179586f * (float)r / (float)(4 * Ns);
    float s1, c1;
    __sincosf(th, &s1, &c1);
    w1 = make_float2(c1, s1);
    w2 = make_float2(c1 * c1 - s1 * s1, 2.0f * c1 * s1);
    w3 = make_float2(w2.x * c1 - w2.y * s1, w2.y * c1 + w2.x * s1);
}

__device__ __forceinline__ Tw make_tw(int lane) {
    Tw t;
    tw_one(lane, 4,  t.a1, t.a2, t.a3);
    tw_one(lane, 16, t.b1, t.b2, t.b3);
    tw_one(lane, 64, t.c1, t.c2, t.c3);
    return t;
}

template<int NS, int DIR>
__device__ __forceinline__ void stage(const float2* s, float2* d, int j,
                                      float2 w1, float2 w2, float2 w3)
{
    float2 v0 = s[PHX(j)];
    float2 v1 = s[PHX(j + 64)];
    float2 v2 = s[PHX(j + 128)];
    float2 v3 = s[PHX(j + 192)];
    if (NS > 1) {
        v1 = cmulf(v1, w1);
        v2 = cmulf(v2, w2);
        v3 = cmulf(v3, w3);
    }
    float t0x = v0.x + v2.x, t0y = v0.y + v2.y;
    float t1x = v0.x - v2.x, t1y = v0.y - v2.y;
    float t2x = v1.x + v3.x, t2y = v1.y + v3.y;
    float t3x = v1.x - v3.x, t3y = v1.y - v3.y;
    float ix = (DIR < 0) ? t3y : -t3y;
    float iy = (DIR < 0) ? -t3x : t3x;
    int r = j & (NS - 1);
    int base = ((j & ~(NS - 1)) << 2) | r;
    d[PHX(base)]          = make_float2(t0x + t2x, t0y + t2y);
    d[PHX(base + NS)]     = make_float2(t1x + ix, t1y + iy);
    d[PHX(base + 2*NS)]   = make_float2(t0x - t2x, t0y - t2y);
    d[PHX(base + 3*NS)]   = make_float2(t1x - ix, t1y - iy);
}

template<int DIR>
__device__ __forceinline__ void fft256(float2* b0, float2* b1, int lane, const Tw& t)
{
    const float sg = (DIR < 0) ? 1.0f : -1.0f;
    float2 a1 = make_float2(t.a1.x, sg * t.a1.y), a2 = make_float2(t.a2.x, sg * t.a2.y),
           a3 = make_float2(t.a3.x, sg * t.a3.y);
    float2 bb1 = make_float2(t.b1.x, sg * t.b1.y), bb2 = make_float2(t.b2.x, sg * t.b2.y),
           bb3 = make_float2(t.b3.x, sg * t.b3.y);
    float2 cc1 = make_float2(t.c1.x, sg * t.c1.y), cc2 = make_float2(t.c2.x, sg * t.c2.y),
           cc3 = make_float2(t.c3.x, sg * t.c3.y);
    wave_sync();
    stage<1,  DIR>(b0, b1, lane, a1, a1, a1);
    wave_sync();
    stage<4,  DIR>(b1, b0, lane, a1, a2, a3);
    wave_sync();
    stage<16, DIR>(b0, b1, lane, bb1, bb2, bb3);
    wave_sync();
    stage<64, DIR>(b1, b0, lane, cc1, cc2, cc3);
    wave_sync();
}

// ---------------- K0: weight transpose -> wt[c][wf][h] float2 ----------------
__global__ __launch_bounds__(256) void k_wt(const float* __restrict__ wre,
                                            const float* __restrict__ wim,
                                            float2* __restrict__ wt)
{
    __shared__ float tr[32 * 129];
    __shared__ float ti[32 * 129];
    const int c  = blockIdx.x >> 3;
    const int h0 = (blockIdx.x & 7) * 32;
    const float* pr = wre + ((size_t)c * 256 + h0) * 129;
    const float* pi = wim + ((size_t)c * 256 + h0) * 129;
    for (int idx = threadIdx.x; idx < 32 * 129; idx += 256) {
        tr[idx] = pr[idx];
        ti[idx] = pi[idx];
    }
    __syncthreads();
    for (int idx = threadIdx.x; idx < 129 * 32; idx += 256) {
        int wf = idx >> 5, hl = idx & 31;
        wt[((size_t)c * 129 + wf) * 256 + h0 + hl] =
            make_float2(tr[hl * 129 + wf], ti[hl * 129 + wf]);
    }
}

// ---------------- K1: row-pair r2c, packed output ----------------
__global__ __launch_bounds__(256) void k_rows_fwd(const float* __restrict__ x,
                                                  float* __restrict__ ws)
{
    __shared__ float2 buf[2][4][256];
    const int lane = threadIdx.x & 63;
    const int wv   = threadIdx.x >> 6;
    const int rp   = blockIdx.x * 4 + wv;
    const float* srcA = x + (size_t)rp * 512;
    const float* srcB = srcA + 256;

    Tw tw = make_tw(lane);

    float4 av = nt_load4(srcA + lane * 4);
    float4 bv = nt_load4(srcB + lane * 4);
    float2* B0 = buf[0][wv];
    float2* B1 = buf[1][wv];
    B0[PHX(4*lane + 0)] = make_float2(av.x, bv.x);
    B0[PHX(4*lane + 1)] = make_float2(av.y, bv.y);
    B0[PHX(4*lane + 2)] = make_float2(av.z, bv.z);
    B0[PHX(4*lane + 3)] = make_float2(av.w, bv.w);

    fft256<-1>(B0, B1, lane, tw);

    const float2* F = B0;
    float4 oa, ob;
    if (lane == 0) {
        float2 Z0 = F[PHX(0)], Z128 = F[PHX(128)];
        float2 Z1 = F[PHX(1)], Zm = F[PHX(255)];
        float2 A1 = make_float2(0.5f * (Z1.x + Zm.x), 0.5f * (Z1.y - Zm.y));
        float2 Bd = make_float2(0.5f * (Z1.x - Zm.x), 0.5f * (Z1.y + Zm.y));
        float2 B1f = make_float2(Bd.y, -Bd.x);
        oa = make_float4(Z0.x, Z128.x, A1.x, A1.y);
        ob = make_float4(Z0.y, Z128.y, B1f.x, B1f.y);
    } else {
        int k0 = 2 * lane;
        float2 Zk0 = F[PHX(k0)],     Zm0 = F[PHX(256 - k0)];
        float2 Zk1 = F[PHX(k0 + 1)], Zm1 = F[PHX(255 - k0)];
        float2 A0 = make_float2(0.5f * (Zk0.x + Zm0.x), 0.5f * (Zk0.y - Zm0.y));
        float2 D0 = make_float2(0.5f * (Zk0.x - Zm0.x), 0.5f * (Zk0.y + Zm0.y));
        float2 Bf0 = make_float2(D0.y, -D0.x);
        float2 A1 = make_float2(0.5f * (Zk1.x + Zm1.x), 0.5f * (Zk1.y - Zm1.y));
        float2 D1 = make_float2(0.5f * (Zk1.x - Zm1.x), 0.5f * (Zk1.y + Zm1.y));
        float2 Bf1 = make_float2(D1.y, -D1.x);
        oa = make_float4(A0.x, A0.y, A1.x, A1.y);
        ob = make_float4(Bf0.x, Bf0.y, Bf1.x, Bf1.y);
    }
    float* dstA = ws + (size_t)rp * 512;
    *(float4*)(dstA + lane * 4)       = oa;
    *(float4*)(dstA + 256 + lane * 4) = ob;
}

// ---------------- K2: register-column FFT + multiply + inverse ----------------
template<bool USEWT>
__global__ __launch_bounds__(256) void k_cols_r(float* __restrict__ ws,
                                                const float2* __restrict__ wt,
                                                const float* __restrict__ wre,
                                                const float* __restrict__ wim)
{
    // 16 group areas, stride 273 (== 1 mod 16 -> groups spread across banks).
    __shared__ float2 A[16][273];                    // 34.9 KiB
    const int tid = threadIdx.x;
    const int l   = tid & 15;                        // lane-in-group
    const int gk  = tid >> 4;                        // group 0..15 = local pair
    // XCD swizzle (8192 % 8 == 0, bijective)
    const int nwg = gridDim.x;
    const int Lb  = (blockIdx.x & 7) * (nwg >> 3) + (blockIdx.x >> 3);
    const int pg  = Lb & 7;                          // pair-group (16 pairs)
    const int img = Lb >> 3;                         // b*C + c
    const int c   = img & 63;
    const int p0  = pg * 16;
    const int pair = p0 + gk;
    float* base = ws + (size_t)img * 65536;
    float2* Ag = A[gk];
    const float gn = 1.0f / 65536.0f;                // ifft2 normalization

    // Prefetch this lane's weights w[c][pair][l+16*k2] (hidden under staging+FFT).
    float2 W[16];
    if (USEWT) {
        const float2* wp = wt + ((size_t)c * 129 + pair) * 256;
#pragma unroll
        for (int k2 = 0; k2 < 16; ++k2) W[k2] = wp[l + 16 * k2];
    } else {
#pragma unroll
        for (int k2 = 0; k2 < 16; ++k2) {
            int ik = (c * 256 + l + 16 * k2) * 129 + pair;
            W[k2] = make_float2(wre[ik], wim[ik]);
        }
    }

    // Cooperative coalesced load: 256 rows x 32 floats (16 pairs).
#pragma unroll
    for (int i = 0; i < 8; ++i) {
        int idx = tid + 256 * i;
        int h = idx >> 3, q = idx & 7;
        float4 xv = *(const float4*)(base + h * 256 + p0 * 2 + q * 4);
        A[2*q    ][h] = make_float2(xv.x, xv.y);
        A[2*q + 1][h] = make_float2(xv.z, xv.w);
    }
    __syncthreads();

    // Strided read: v[n1] = column value at h = 16*n1 + l  (conflict-free).
    float2 v[16];
#pragma unroll
    for (int n1 = 0; n1 < 16; ++n1) v[n1] = Ag[16 * n1 + l];

    gfft<-1>(v, Ag, l);                              // v[k2] = S^[l + 16*k2]

    if (pair == 0) {
        // Two packed real columns: untangle via one LDS exchange, multiply by
        // Hermitian-projected weights, repack y0 + i*y1.
        wave_sync();
#pragma unroll
        for (int k2 = 0; k2 < 16; ++k2) Ag[l + 16 * k2] = v[k2];   // linear by k
        wave_sync();
        float2 sm[16];
#pragma unroll
        for (int k2 = 0; k2 < 16; ++k2) {
            int m = (256 - (l + 16 * k2)) & 255;
            sm[k2] = Ag[m];
        }
#pragma unroll
        for (int k2 = 0; k2 < 16; ++k2) {
            int k = l + 16 * k2;
            int m = (256 - k) & 255;
            float2 Sk = v[k2], Sm = sm[k2];
            float2 S0   = make_float2(0.5f * (Sk.x + Sm.x), 0.5f * (Sk.y - Sm.y));
            float2 Dk   = make_float2(0.5f * (Sk.x - Sm.x), 0.5f * (Sk.y + Sm.y));
            float2 S128 = make_float2(Dk.y, -Dk.x);             // -i * Dk
            float2 wk0, wm0, wk128, wm128;
            if (USEWT) {
                const float2* w0r   = wt + ((size_t)c * 129 +   0) * 256;
                const float2* w128r = wt + ((size_t)c * 129 + 128) * 256;
                wk0 = W[k2];  wm0 = w0r[m];
                wk128 = w128r[k];  wm128 = w128r[m];
            } else {
                int ik = (c * 256 + k) * 129, im = (c * 256 + m) * 129;
                wk0   = make_float2(wre[ik], wim[ik]);
                wm0   = make_float2(wre[im], wim[im]);
                wk128 = make_float2(wre[ik + 128], wim[ik + 128]);
                wm128 = make_float2(wre[im + 128], wim[im + 128]);
            }
            float2 A0   = make_float2(0.5f * gn * (wk0.x + wm0.x),
                                      0.5f * gn * (wk0.y - wm0.y));
            float2 A128 = make_float2(0.5f * gn * (wk128.x + wm128.x),
                                      0.5f * gn * (wk128.y - wm128.y));
            float2 y0 = cmulf(S0, A0);
            float2 y1 = cmulf(S128, A128);
            v[k2] = make_float2(y0.x - y1.y, y0.y + y1.x);      // y0 + i*y1
        }
    } else {
#pragma unroll
        for (int k2 = 0; k2 < 16; ++k2)
            v[k2] = cmulf(v[k2], make_float2(gn * W[k2].x, gn * W[k2].y));
    }

    gfft<+1>(v, Ag, l);                              // v[k2] = z[l + 16*k2]

    // Restage (strided, conflict-free), then cooperative coalesced store.
    wave_sync();
#pragma unroll
    for (int k2 = 0; k2 < 16; ++k2) Ag[l + 16 * k2] = v[k2];
    __syncthreads();
#pragma unroll
    for (int i = 0; i < 8; ++i) {
        int idx = tid + 256 * i;
        int h = idx >> 3, q = idx & 7;
        float2 a = A[2*q    ][h];
        float2 b = A[2*q + 1][h];
        *(float4*)(base + h * 256 + p0 * 2 + q * 4) = make_float4(a.x, a.y, b.x, b.y);
    }
}

// ---------------- K3: row-pair c2r, in place ----------------
__global__ __launch_bounds__(256) void k_rows_inv(float* __restrict__ ws)
{
    __shared__ float2 buf[2][4][256];
    const int lane = threadIdx.x & 63;
    const int wv   = threadIdx.x >> 6;
    const int rp   = blockIdx.x * 4 + wv;
    float* rowA = ws + (size_t)rp * 512;
    float* rowB = rowA + 256;

    Tw tw = make_tw(lane);

    float4 va = *(const float4*)(rowA + lane * 4);
    float4 vb = *(const float4*)(rowB + lane * 4);
    float2* B0 = buf[0][wv];
    float2* B1 = buf[1][wv];
    if (lane == 0) {
        B0[PHX(0)]   = make_float2(va.x, vb.x);
        B0[PHX(128)] = make_float2(va.y, vb.y);
        B0[PHX(1)]   = make_float2(va.z - vb.w, va.w + vb.z);
        B0[PHX(255)] = make_float2(va.z + vb.w, -va.w + vb.z);
    } else {
        int k0 = 2 * lane;
        B0[PHX(k0)]        = make_float2(va.x - vb.y, va.y + vb.x);
        B0[PHX(256 - k0)]  = make_float2(va.x + vb.y, -va.y + vb.x);
        B0[PHX(k0 + 1)]    = make_float2(va.z - vb.w, va.w + vb.z);
        B0[PHX(255 - k0)]  = make_float2(va.z + vb.w, -va.w + vb.z);
    }

    fft256<+1>(B0, B1, lane, tw);

    const float2* F = B0;
    float2 f0 = F[PHX(4*lane)], f1 = F[PHX(4*lane + 1)];
    float2 f2 = F[PHX(4*lane + 2)], f3 = F[PHX(4*lane + 3)];
    nt_store4(rowA + lane * 4, make_float4(f0.x, f1.x, f2.x, f3.x));
    nt_store4(rowB + lane * 4, make_float4(f0.y, f1.y, f2.y, f3.y));
}

extern "C" void kernel_launch(void* const* d_in, const int* in_sizes, int n_in,
                              void* d_out, int out_size, void* d_ws, size_t ws_size,
                              hipStream_t stream)
{
    (void)in_sizes; (void)n_in; (void)out_size;
    const float* x   = (const float*)d_in[0];
    const float* wre = (const float*)d_in[1];
    const float* wim = (const float*)d_in[2];
    float* out = (float*)d_out;
    float2* wt = (float2*)d_ws;

    const size_t wt_bytes = (size_t)64 * 129 * 256 * sizeof(float2);  // 16.9 MB
    const bool use_wt = (ws_size >= wt_bytes);

    if (use_wt) {
        k_wt<<<dim3(512), dim3(256), 0, stream>>>(wre, wim, wt);
    }
    // B*C*H/2 = 131072 row pairs, 4 per block
    k_rows_fwd<<<dim3(32768), dim3(256), 0, stream>>>(x, out);
    // 1024 images x 8 pair-groups (16 pairs per block)
    if (use_wt)
        k_cols_r<true ><<<dim3(8192), dim3(256), 0, stream>>>(out, wt, wre, wim);
    else
        k_cols_r<false><<<dim3(8192), dim3(256), 0, stream>>>(out, wt, wre, wim);
    k_rows_inv<<<dim3(32768), dim3(256), 0, stream>>>(out);
}